// Round 1
// baseline (250.133 us; speedup 1.0000x reference)
//
#include <hip/hip_runtime.h>
#include <hip/hip_bf16.h>

#define B_ 128
#define H_ 2048
#define E_ 1024
#define D_ 512

// ---------------------------------------------------------------------------
// Kernel 1: q[b,d] = dot(cur[b,:], Wq[d,:]) + bq[d]     (one wave per output)
// ---------------------------------------------------------------------------
__global__ __launch_bounds__(256) void k_q(const float* __restrict__ cur,
                                           const float* __restrict__ Wq,
                                           const float* __restrict__ bq,
                                           float* __restrict__ q) {
    int wid  = (blockIdx.x * 256 + threadIdx.x) >> 6;  // global wave id
    int lane = threadIdx.x & 63;
    int b = wid >> 9;          // / D_ (512)
    int d = wid & (D_ - 1);

    const float4* cur4 = reinterpret_cast<const float4*>(cur + (size_t)b * E_);
    const float4* wq4  = reinterpret_cast<const float4*>(Wq  + (size_t)d * E_);

    float acc = 0.f;
#pragma unroll
    for (int it = 0; it < 4; ++it) {           // E/4 = 256 float4, 64 lanes
        int idx = lane + it * 64;
        float4 c = cur4[idx];
        float4 w = wq4[idx];
        acc += c.x * w.x + c.y * w.y + c.z * w.z + c.w * w.w;
    }
#pragma unroll
    for (int off = 32; off >= 1; off >>= 1) acc += __shfl_xor(acc, off, 64);
    if (lane == 0) q[(size_t)b * D_ + d] = acc + bq[d];
}

// ---------------------------------------------------------------------------
// Kernel 2: qW[b,e] = sum_d q[b,d]*Wk[d,e];  qb[b] = sum_d q[b,d]*bk[d]
// One block per b; coalesced column sweep over Wk rows.
// ---------------------------------------------------------------------------
__global__ __launch_bounds__(256) void k_qw(const float* __restrict__ q,
                                            const float* __restrict__ Wk,
                                            const float* __restrict__ bk,
                                            float* __restrict__ qW,
                                            float* __restrict__ qb) {
    __shared__ float qs[D_];
    __shared__ float red[256];
    int b = blockIdx.x;
    int t = threadIdx.x;

    for (int d = t; d < D_; d += 256) qs[d] = q[(size_t)b * D_ + d];
    __syncthreads();

    float a0 = 0.f, a1 = 0.f, a2 = 0.f, a3 = 0.f;
    for (int d = 0; d < D_; ++d) {
        float qd = qs[d];
        const float* wr = Wk + (size_t)d * E_;
        a0 = fmaf(qd, wr[t        ], a0);
        a1 = fmaf(qd, wr[t + 256  ], a1);
        a2 = fmaf(qd, wr[t + 512  ], a2);
        a3 = fmaf(qd, wr[t + 768  ], a3);
    }
    float* o = qW + (size_t)b * E_;
    o[t] = a0; o[t + 256] = a1; o[t + 512] = a2; o[t + 768] = a3;

    float pb = 0.f;
    for (int d = t; d < D_; d += 256) pb = fmaf(qs[d], bk[d], pb);
    red[t] = pb;
    __syncthreads();
    for (int s = 128; s >= 1; s >>= 1) {
        if (t < s) red[t] += red[t + s];
        __syncthreads();
    }
    if (t == 0) qb[b] = red[0];
}

// ---------------------------------------------------------------------------
// Kernel 3: streaming pass over hist. One wave handles HCHUNK consecutive h
// rows; cur[b] and qW[b] live in registers across the chunk.
// out[b,h] = w_att*(hist.qW + qb)/sqrt(D) + w_cos * hist.cur/(ncur*nhist)
// ---------------------------------------------------------------------------
#define HCHUNK 8

__global__ __launch_bounds__(256) void k_main(const float* __restrict__ cur,
                                              const float* __restrict__ hist,
                                              const float* __restrict__ qW,
                                              const float* __restrict__ qb,
                                              const float* __restrict__ w_cos_p,
                                              const float* __restrict__ w_att_p,
                                              float* __restrict__ out) {
    int wid  = (blockIdx.x * 256 + threadIdx.x) >> 6;
    int lane = threadIdx.x & 63;
    int b  = wid / (H_ / HCHUNK);
    int hc = wid % (H_ / HCHUNK);
    int h0 = hc * HCHUNK;

    const float4* cur4 = reinterpret_cast<const float4*>(cur + (size_t)b * E_);
    const float4* qW4  = reinterpret_cast<const float4*>(qW  + (size_t)b * E_);

    float4 c[4], w[4];
    float css = 0.f;
#pragma unroll
    for (int it = 0; it < 4; ++it) {
        c[it] = cur4[lane + it * 64];
        w[it] = qW4[lane + it * 64];
        css += c[it].x * c[it].x + c[it].y * c[it].y +
               c[it].z * c[it].z + c[it].w * c[it].w;
    }
#pragma unroll
    for (int off = 32; off >= 1; off >>= 1) css += __shfl_xor(css, off, 64);
    float n_cur = fmaxf(sqrtf(css), 1e-8f);

    float wc  = w_cos_p[0];
    float wa  = w_att_p[0];
    float qbb = qb[b];
    const float inv_sqrtD = 0.04419417382415922f;  // 1/sqrt(512)

    for (int j = 0; j < HCHUNK; ++j) {
        int h = h0 + j;
        const float4* h4 =
            reinterpret_cast<const float4*>(hist + ((size_t)b * H_ + h) * E_);
        float a_dot = 0.f, a_qw = 0.f, a_ss = 0.f;
#pragma unroll
        for (int it = 0; it < 4; ++it) {
            float4 hv = h4[lane + it * 64];
            a_dot += hv.x * c[it].x + hv.y * c[it].y + hv.z * c[it].z + hv.w * c[it].w;
            a_qw  += hv.x * w[it].x + hv.y * w[it].y + hv.z * w[it].z + hv.w * w[it].w;
            a_ss  += hv.x * hv.x   + hv.y * hv.y   + hv.z * hv.z   + hv.w * hv.w;
        }
#pragma unroll
        for (int off = 32; off >= 1; off >>= 1) {
            a_dot += __shfl_xor(a_dot, off, 64);
            a_qw  += __shfl_xor(a_qw,  off, 64);
            a_ss  += __shfl_xor(a_ss,  off, 64);
        }
        if (lane == 0) {
            float n_hist = fmaxf(sqrtf(a_ss), 1e-8f);
            float cosv   = a_dot / (n_cur * n_hist);
            float score  = (a_qw + qbb) * inv_sqrtD;
            out[(size_t)b * H_ + h] = wa * score + wc * cosv;
        }
    }
}

// ---------------------------------------------------------------------------
extern "C" void kernel_launch(void* const* d_in, const int* in_sizes, int n_in,
                              void* d_out, int out_size, void* d_ws, size_t ws_size,
                              hipStream_t stream) {
    const float* cur   = (const float*)d_in[0];
    const float* hist  = (const float*)d_in[1];
    const float* Wq    = (const float*)d_in[2];
    const float* bq    = (const float*)d_in[3];
    const float* Wk    = (const float*)d_in[4];
    const float* bk    = (const float*)d_in[5];
    const float* w_cos = (const float*)d_in[6];
    const float* w_att = (const float*)d_in[7];
    float* out = (float*)d_out;

    float* ws = (float*)d_ws;
    float* q  = ws;                        // B*D   floats (256 KB)
    float* qW = ws + (size_t)B_ * D_;      // B*E   floats (512 KB)
    float* qb = qW + (size_t)B_ * E_;      // B     floats

    // q = cur @ Wq.T + bq
    k_q<<<(B_ * D_) / 4, 256, 0, stream>>>(cur, Wq, bq, q);
    // qW = q @ Wk ; qb = q . bk
    k_qw<<<B_, 256, 0, stream>>>(q, Wk, bk, qW, qb);
    // streaming fused pass
    int waves = B_ * (H_ / HCHUNK);        // 32768 waves
    k_main<<<waves / 4, 256, 0, stream>>>(cur, hist, qW, qb, w_cos, w_att, out);
}

// Round 2
// 235.211 us; speedup vs baseline: 1.0634x; 1.0634x over previous
//
#include <hip/hip_runtime.h>
#include <hip/hip_bf16.h>

#define B_ 128
#define H_ 2048
#define E_ 1024
#define D_ 512

// ---------------------------------------------------------------------------
// Kernel 1: q[b,d] = dot(cur[b,:], Wq[d,:]) + bq[d]
// 4b x 4d register tile per wave: 32KB L2 reads per 16 outputs (4x less
// traffic than wave-per-output).
// ---------------------------------------------------------------------------
__global__ __launch_bounds__(256) void k_q(const float* __restrict__ cur,
                                           const float* __restrict__ Wq,
                                           const float* __restrict__ bq,
                                           float* __restrict__ q) {
    int wid  = (blockIdx.x * 256 + threadIdx.x) >> 6;
    int lane = threadIdx.x & 63;
    int bg = wid >> 7;            // D_/4 = 128 d-groups per b-group
    int dg = wid & 127;
    int b0 = bg * 4, d0 = dg * 4;

    float4 c[4][4];
#pragma unroll
    for (int i = 0; i < 4; ++i) {
        const float4* cur4 =
            reinterpret_cast<const float4*>(cur + (size_t)(b0 + i) * E_);
#pragma unroll
        for (int it = 0; it < 4; ++it) c[i][it] = cur4[lane + it * 64];
    }

#pragma unroll
    for (int dd = 0; dd < 4; ++dd) {
        const float4* wq4 =
            reinterpret_cast<const float4*>(Wq + (size_t)(d0 + dd) * E_);
        float4 w[4];
#pragma unroll
        for (int it = 0; it < 4; ++it) w[it] = wq4[lane + it * 64];

        float acc[4] = {0.f, 0.f, 0.f, 0.f};
#pragma unroll
        for (int i = 0; i < 4; ++i)
#pragma unroll
            for (int it = 0; it < 4; ++it)
                acc[i] += c[i][it].x * w[it].x + c[i][it].y * w[it].y +
                          c[i][it].z * w[it].z + c[i][it].w * w[it].w;
#pragma unroll
        for (int off = 32; off >= 1; off >>= 1)
#pragma unroll
            for (int i = 0; i < 4; ++i) acc[i] += __shfl_xor(acc[i], off, 64);

        if (lane == 0) {
            float bqv = bq[d0 + dd];
#pragma unroll
            for (int i = 0; i < 4; ++i)
                q[(size_t)(b0 + i) * D_ + (d0 + dd)] = acc[i] + bqv;
        }
    }
}

// ---------------------------------------------------------------------------
// Kernel 2: qW[b,e] = sum_d q[b,d]*Wk[d,e];  qb[b] = sum_d q[b,d]*bk[d]
// 2 b's per block x 4 e-chunks -> 256 blocks (all CUs), Wk row slice read
// once per 2 b's. Coalesced column sweep.
// ---------------------------------------------------------------------------
__global__ __launch_bounds__(256) void k_qw(const float* __restrict__ q,
                                            const float* __restrict__ Wk,
                                            const float* __restrict__ bk,
                                            float* __restrict__ qW,
                                            float* __restrict__ qb) {
    __shared__ float qs[2][D_];
    int blk = blockIdx.x;
    int bp  = blk >> 2;          // b-pair 0..63
    int ec  = blk & 3;           // e-chunk 0..3
    int t   = threadIdx.x;
    int b0  = bp * 2;
    int e   = ec * 256 + t;

    for (int d = t; d < D_; d += 256) {
        qs[0][d] = q[(size_t)b0 * D_ + d];
        qs[1][d] = q[(size_t)(b0 + 1) * D_ + d];
    }
    __syncthreads();

    float a0 = 0.f, a1 = 0.f;
#pragma unroll 8
    for (int d = 0; d < D_; ++d) {
        float wv = Wk[(size_t)d * E_ + e];
        a0 = fmaf(qs[0][d], wv, a0);
        a1 = fmaf(qs[1][d], wv, a1);
    }
    qW[(size_t)b0 * E_ + e]       = a0;
    qW[(size_t)(b0 + 1) * E_ + e] = a1;

    if (ec == 0) {
        float p0 = 0.f, p1 = 0.f;
        for (int d = t; d < D_; d += 256) {
            float bkv = bk[d];
            p0 = fmaf(qs[0][d], bkv, p0);
            p1 = fmaf(qs[1][d], bkv, p1);
        }
        __shared__ float r0[256], r1[256];
        r0[t] = p0; r1[t] = p1;
        __syncthreads();
        for (int s = 128; s >= 1; s >>= 1) {
            if (t < s) { r0[t] += r0[t + s]; r1[t] += r1[t + s]; }
            __syncthreads();
        }
        if (t == 0) { qb[b0] = r0[0]; qb[b0 + 1] = r1[0]; }
    }
}

// ---------------------------------------------------------------------------
// Kernel 3: streaming pass over hist. One wave handles HCHUNK consecutive h
// rows. Phase A: intra-lane partials for all rows (loads pipeline freely
// across rows). Phase B: batched butterfly reductions + store.
// out[b,h] = w_att*(hist.qW + qb)/sqrt(D) + w_cos * hist.cur/(ncur*nhist)
// ---------------------------------------------------------------------------
#define HCHUNK 8

__global__ __launch_bounds__(256) void k_main(const float* __restrict__ cur,
                                              const float* __restrict__ hist,
                                              const float* __restrict__ qW,
                                              const float* __restrict__ qb,
                                              const float* __restrict__ w_cos_p,
                                              const float* __restrict__ w_att_p,
                                              float* __restrict__ out) {
    int wid  = (blockIdx.x * 256 + threadIdx.x) >> 6;
    int lane = threadIdx.x & 63;
    int b  = wid / (H_ / HCHUNK);
    int hc = wid % (H_ / HCHUNK);
    int h0 = hc * HCHUNK;

    const float4* cur4 = reinterpret_cast<const float4*>(cur + (size_t)b * E_);
    const float4* qW4  = reinterpret_cast<const float4*>(qW  + (size_t)b * E_);

    float4 c[4], w[4];
    float css = 0.f;
#pragma unroll
    for (int it = 0; it < 4; ++it) {
        c[it] = cur4[lane + it * 64];
        w[it] = qW4[lane + it * 64];
        css += c[it].x * c[it].x + c[it].y * c[it].y +
               c[it].z * c[it].z + c[it].w * c[it].w;
    }
#pragma unroll
    for (int off = 32; off >= 1; off >>= 1) css += __shfl_xor(css, off, 64);
    float n_cur = fmaxf(sqrtf(css), 1e-8f);

    float wc  = w_cos_p[0];
    float wa  = w_att_p[0];
    float qbb = qb[b];
    const float inv_sqrtD = 0.04419417382415922f;  // 1/sqrt(512)

    float ad[HCHUNK], aq[HCHUNK], as_[HCHUNK];

    // Phase A: intra-lane accumulation, all rows
#pragma unroll
    for (int j = 0; j < HCHUNK; ++j) {
        const float4* h4 = reinterpret_cast<const float4*>(
            hist + ((size_t)b * H_ + (h0 + j)) * E_);
        float t_dot = 0.f, t_qw = 0.f, t_ss = 0.f;
#pragma unroll
        for (int it = 0; it < 4; ++it) {
            float4 hv = h4[lane + it * 64];
            t_dot += hv.x * c[it].x + hv.y * c[it].y + hv.z * c[it].z + hv.w * c[it].w;
            t_qw  += hv.x * w[it].x + hv.y * w[it].y + hv.z * w[it].z + hv.w * w[it].w;
            t_ss  += hv.x * hv.x   + hv.y * hv.y   + hv.z * hv.z   + hv.w * hv.w;
        }
        ad[j] = t_dot; aq[j] = t_qw; as_[j] = t_ss;
    }

    // Phase B: batched butterflies
#pragma unroll
    for (int off = 32; off >= 1; off >>= 1) {
#pragma unroll
        for (int j = 0; j < HCHUNK; ++j) {
            ad[j]  += __shfl_xor(ad[j],  off, 64);
            aq[j]  += __shfl_xor(aq[j],  off, 64);
            as_[j] += __shfl_xor(as_[j], off, 64);
        }
    }

    if (lane == 0) {
#pragma unroll
        for (int j = 0; j < HCHUNK; ++j) {
            float n_hist = fmaxf(sqrtf(as_[j]), 1e-8f);
            float cosv   = ad[j] / (n_cur * n_hist);
            float score  = (aq[j] + qbb) * inv_sqrtD;
            out[(size_t)b * H_ + (h0 + j)] = wa * score + wc * cosv;
        }
    }
}

// ---------------------------------------------------------------------------
extern "C" void kernel_launch(void* const* d_in, const int* in_sizes, int n_in,
                              void* d_out, int out_size, void* d_ws, size_t ws_size,
                              hipStream_t stream) {
    const float* cur   = (const float*)d_in[0];
    const float* hist  = (const float*)d_in[1];
    const float* Wq    = (const float*)d_in[2];
    const float* bq    = (const float*)d_in[3];
    const float* Wk    = (const float*)d_in[4];
    const float* bk    = (const float*)d_in[5];
    const float* w_cos = (const float*)d_in[6];
    const float* w_att = (const float*)d_in[7];
    float* out = (float*)d_out;

    float* ws = (float*)d_ws;
    float* q  = ws;                        // B*D floats
    float* qW = ws + (size_t)B_ * D_;      // B*E floats
    float* qb = qW + (size_t)B_ * E_;      // B   floats

    // q = cur @ Wq.T + bq   (4096 waves -> 1024 blocks)
    k_q<<<(B_ / 4) * (D_ / 4) / 4, 256, 0, stream>>>(cur, Wq, bq, q);
    // qW = q @ Wk ; qb = q . bk   (256 blocks)
    k_qw<<<(B_ / 2) * 4, 256, 0, stream>>>(q, Wk, bk, qW, qb);
    // streaming fused pass (32768 waves -> 8192 blocks)
    k_main<<<B_ * (H_ / HCHUNK) / 4, 256, 0, stream>>>(cur, hist, qW, qb,
                                                       w_cos, w_att, out);
}

// Round 4
// 213.076 us; speedup vs baseline: 1.1739x; 1.1039x over previous
//
#include <hip/hip_runtime.h>
#include <hip/hip_bf16.h>

#define B_ 128
#define H_ 2048
#define E_ 1024
#define D_ 512

typedef float f32x4 __attribute__((ext_vector_type(4)));

// ---------------------------------------------------------------------------
// Kernel 1: q[b,d] = dot(cur[b,:], Wq[d,:]) + bq[d]
// 4b x 4d register tile per wave.
// ---------------------------------------------------------------------------
__global__ __launch_bounds__(256) void k_q(const float* __restrict__ cur,
                                           const float* __restrict__ Wq,
                                           const float* __restrict__ bq,
                                           float* __restrict__ q) {
    int wid  = (blockIdx.x * 256 + threadIdx.x) >> 6;
    int lane = threadIdx.x & 63;
    int bg = wid >> 7;            // D_/4 = 128 d-groups per b-group
    int dg = wid & 127;
    int b0 = bg * 4, d0 = dg * 4;

    float4 c[4][4];
#pragma unroll
    for (int i = 0; i < 4; ++i) {
        const float4* cur4 =
            reinterpret_cast<const float4*>(cur + (size_t)(b0 + i) * E_);
#pragma unroll
        for (int it = 0; it < 4; ++it) c[i][it] = cur4[lane + it * 64];
    }

#pragma unroll
    for (int dd = 0; dd < 4; ++dd) {
        const float4* wq4 =
            reinterpret_cast<const float4*>(Wq + (size_t)(d0 + dd) * E_);
        float4 w[4];
#pragma unroll
        for (int it = 0; it < 4; ++it) w[it] = wq4[lane + it * 64];

        float acc[4] = {0.f, 0.f, 0.f, 0.f};
#pragma unroll
        for (int i = 0; i < 4; ++i)
#pragma unroll
            for (int it = 0; it < 4; ++it)
                acc[i] += c[i][it].x * w[it].x + c[i][it].y * w[it].y +
                          c[i][it].z * w[it].z + c[i][it].w * w[it].w;
#pragma unroll
        for (int off = 32; off >= 1; off >>= 1)
#pragma unroll
            for (int i = 0; i < 4; ++i) acc[i] += __shfl_xor(acc[i], off, 64);

        if (lane == 0) {
            float bqv = bq[d0 + dd];
#pragma unroll
            for (int i = 0; i < 4; ++i)
                q[(size_t)(b0 + i) * D_ + (d0 + dd)] = acc[i] + bqv;
        }
    }
}

// ---------------------------------------------------------------------------
// Kernel 2: qW[b,e] = sum_d q[b,d]*Wk[d,e];  qb[b] = sum_d q[b,d]*bk[d]
// 512 blocks (b x 4 e-chunks): 2 blocks/CU so L2 latency is covered by
// 2 waves/SIMD; unroll 16.
// ---------------------------------------------------------------------------
__global__ __launch_bounds__(256) void k_qw(const float* __restrict__ q,
                                            const float* __restrict__ Wk,
                                            const float* __restrict__ bk,
                                            float* __restrict__ qW,
                                            float* __restrict__ qb) {
    __shared__ float qs[D_];
    int b  = blockIdx.x >> 2;
    int ec = blockIdx.x & 3;
    int t  = threadIdx.x;
    int e  = ec * 256 + t;

    for (int d = t; d < D_; d += 256) qs[d] = q[(size_t)b * D_ + d];
    __syncthreads();

    float a = 0.f;
#pragma unroll 16
    for (int d = 0; d < D_; ++d)
        a = fmaf(qs[d], Wk[(size_t)d * E_ + e], a);
    qW[(size_t)b * E_ + e] = a;

    if (ec == 0) {
        float p = 0.f;
        for (int d = t; d < D_; d += 256) p = fmaf(qs[d], bk[d], p);
        __shared__ float red[256];
        red[t] = p;
        __syncthreads();
        for (int s = 128; s >= 1; s >>= 1) {
            if (t < s) red[t] += red[t + s];
            __syncthreads();
        }
        if (t == 0) qb[b] = red[0];
    }
}

// ---------------------------------------------------------------------------
// Kernel 3: streaming pass over hist (non-temporal — zero reuse, keep L2
// for cur/qW). One wave handles HCHUNK consecutive h rows.
// Phase A: intra-lane partials (loads pipeline across rows).
// Phase B: batched butterfly reductions + store.
// ---------------------------------------------------------------------------
#define HCHUNK 8

__global__ __launch_bounds__(256) void k_main(const float* __restrict__ cur,
                                              const float* __restrict__ hist,
                                              const float* __restrict__ qW,
                                              const float* __restrict__ qb,
                                              const float* __restrict__ w_cos_p,
                                              const float* __restrict__ w_att_p,
                                              float* __restrict__ out) {
    int wid  = (blockIdx.x * 256 + threadIdx.x) >> 6;
    int lane = threadIdx.x & 63;
    int b  = wid / (H_ / HCHUNK);
    int hc = wid % (H_ / HCHUNK);
    int h0 = hc * HCHUNK;

    const float4* cur4 = reinterpret_cast<const float4*>(cur + (size_t)b * E_);
    const float4* qW4  = reinterpret_cast<const float4*>(qW  + (size_t)b * E_);

    float4 c[4], w[4];
    float css = 0.f;
#pragma unroll
    for (int it = 0; it < 4; ++it) {
        c[it] = cur4[lane + it * 64];
        w[it] = qW4[lane + it * 64];
        css += c[it].x * c[it].x + c[it].y * c[it].y +
               c[it].z * c[it].z + c[it].w * c[it].w;
    }
#pragma unroll
    for (int off = 32; off >= 1; off >>= 1) css += __shfl_xor(css, off, 64);
    float n_cur = fmaxf(sqrtf(css), 1e-8f);

    float wc  = w_cos_p[0];
    float wa  = w_att_p[0];
    float qbb = qb[b];
    const float inv_sqrtD = 0.04419417382415922f;  // 1/sqrt(512)

    float ad[HCHUNK], aq[HCHUNK], as_[HCHUNK];

    // Phase A: intra-lane accumulation, all rows
#pragma unroll
    for (int j = 0; j < HCHUNK; ++j) {
        const f32x4* h4 = reinterpret_cast<const f32x4*>(
            hist + ((size_t)b * H_ + (h0 + j)) * E_);
        float t_dot = 0.f, t_qw = 0.f, t_ss = 0.f;
#pragma unroll
        for (int it = 0; it < 4; ++it) {
            f32x4 hv = __builtin_nontemporal_load(&h4[lane + it * 64]);
            t_dot += hv.x * c[it].x + hv.y * c[it].y + hv.z * c[it].z + hv.w * c[it].w;
            t_qw  += hv.x * w[it].x + hv.y * w[it].y + hv.z * w[it].z + hv.w * w[it].w;
            t_ss  += hv.x * hv.x   + hv.y * hv.y   + hv.z * hv.z   + hv.w * hv.w;
        }
        ad[j] = t_dot; aq[j] = t_qw; as_[j] = t_ss;
    }

    // Phase B: batched butterflies
#pragma unroll
    for (int off = 32; off >= 1; off >>= 1) {
#pragma unroll
        for (int j = 0; j < HCHUNK; ++j) {
            ad[j]  += __shfl_xor(ad[j],  off, 64);
            aq[j]  += __shfl_xor(aq[j],  off, 64);
            as_[j] += __shfl_xor(as_[j], off, 64);
        }
    }

    if (lane == 0) {
#pragma unroll
        for (int j = 0; j < HCHUNK; ++j) {
            float n_hist = fmaxf(sqrtf(as_[j]), 1e-8f);
            float cosv   = ad[j] / (n_cur * n_hist);
            float score  = (aq[j] + qbb) * inv_sqrtD;
            out[(size_t)b * H_ + (h0 + j)] = wa * score + wc * cosv;
        }
    }
}

// ---------------------------------------------------------------------------
extern "C" void kernel_launch(void* const* d_in, const int* in_sizes, int n_in,
                              void* d_out, int out_size, void* d_ws, size_t ws_size,
                              hipStream_t stream) {
    const float* cur   = (const float*)d_in[0];
    const float* hist  = (const float*)d_in[1];
    const float* Wq    = (const float*)d_in[2];
    const float* bq    = (const float*)d_in[3];
    const float* Wk    = (const float*)d_in[4];
    const float* bk    = (const float*)d_in[5];
    const float* w_cos = (const float*)d_in[6];
    const float* w_att = (const float*)d_in[7];
    float* out = (float*)d_out;

    float* ws = (float*)d_ws;
    float* q  = ws;                        // B*D floats
    float* qW = ws + (size_t)B_ * D_;      // B*E floats
    float* qb = qW + (size_t)B_ * E_;      // B   floats

    // q = cur @ Wq.T + bq   (4096 waves -> 1024 blocks)
    k_q<<<(B_ / 4) * (D_ / 4) / 4, 256, 0, stream>>>(cur, Wq, bq, q);
    // qW = q @ Wk ; qb = q . bk   (512 blocks)
    k_qw<<<B_ * 4, 256, 0, stream>>>(q, Wk, bk, qW, qb);
    // streaming fused pass (32768 waves -> 8192 blocks)
    k_main<<<B_ * (H_ / HCHUNK) / 4, 256, 0, stream>>>(cur, hist, qW, qb,
                                                       w_cos, w_att, out);
}

// Round 5
// 189.854 us; speedup vs baseline: 1.3175x; 1.1223x over previous
//
#include <hip/hip_runtime.h>
#include <hip/hip_bf16.h>

#define B_ 128
#define H_ 2048
#define E_ 1024
#define D_ 512

typedef float f32x2 __attribute__((ext_vector_type(2)));
typedef float f32x4 __attribute__((ext_vector_type(4)));

// ---------------------------------------------------------------------------
// Kernel 1: q[b,d] = dot(cur[b,:], Wq[d,:]) + bq[d]
// 4b x 4d register tile per wave.
// ---------------------------------------------------------------------------
__global__ __launch_bounds__(256) void k_q(const float* __restrict__ cur,
                                           const float* __restrict__ Wq,
                                           const float* __restrict__ bq,
                                           float* __restrict__ q) {
    int wid  = (blockIdx.x * 256 + threadIdx.x) >> 6;
    int lane = threadIdx.x & 63;
    int bg = wid >> 7;            // D_/4 = 128 d-groups per b-group
    int dg = wid & 127;
    int b0 = bg * 4, d0 = dg * 4;

    float4 c[4][4];
#pragma unroll
    for (int i = 0; i < 4; ++i) {
        const float4* cur4 =
            reinterpret_cast<const float4*>(cur + (size_t)(b0 + i) * E_);
#pragma unroll
        for (int it = 0; it < 4; ++it) c[i][it] = cur4[lane + it * 64];
    }

#pragma unroll
    for (int dd = 0; dd < 4; ++dd) {
        const float4* wq4 =
            reinterpret_cast<const float4*>(Wq + (size_t)(d0 + dd) * E_);
        float4 w[4];
#pragma unroll
        for (int it = 0; it < 4; ++it) w[it] = wq4[lane + it * 64];

        float acc[4] = {0.f, 0.f, 0.f, 0.f};
#pragma unroll
        for (int i = 0; i < 4; ++i)
#pragma unroll
            for (int it = 0; it < 4; ++it)
                acc[i] += c[i][it].x * w[it].x + c[i][it].y * w[it].y +
                          c[i][it].z * w[it].z + c[i][it].w * w[it].w;
#pragma unroll
        for (int off = 32; off >= 1; off >>= 1)
#pragma unroll
            for (int i = 0; i < 4; ++i) acc[i] += __shfl_xor(acc[i], off, 64);

        if (lane == 0) {
            float bqv = bq[d0 + dd];
#pragma unroll
            for (int i = 0; i < 4; ++i)
                q[(size_t)(b0 + i) * D_ + (d0 + dd)] = acc[i] + bqv;
        }
    }
}

// ---------------------------------------------------------------------------
// Kernel 2: qW[b,e] = sum_d q[b,d]*Wk[d,e];  qb[b] = sum_d q[b,d]*bk[d]
// 512 blocks: 32 b-groups(4) x 16 e-chunks(64). Wk slice read ONCE per block
// (total 64 MB L2 vs 256 MB before). Wave w handles b0+w (wave-aligned), so
// qb reduces with a pure 64-lane butterfly.
// ---------------------------------------------------------------------------
__global__ __launch_bounds__(256) void k_qw(const float* __restrict__ q,
                                            const float* __restrict__ Wk,
                                            const float* __restrict__ bk,
                                            float* __restrict__ qW,
                                            float* __restrict__ qb) {
    __shared__ float qs[4][D_];
    int blk = blockIdx.x;
    int bg  = blk >> 4;           // 0..31
    int ec  = blk & 15;           // 0..15
    int t   = threadIdx.x;
    int b0  = bg * 4;

    for (int i = t; i < 4 * D_; i += 256)
        qs[i >> 9][i & (D_ - 1)] = q[(size_t)(b0 + (i >> 9)) * D_ + (i & (D_ - 1))];
    __syncthreads();

    int eL = t & 63;              // lane
    int bL = t >> 6;              // wave id = local b
    int e  = ec * 64 + eL;

    float a = 0.f;
#pragma unroll 16
    for (int d = 0; d < D_; ++d)
        a = fmaf(qs[bL][d], Wk[(size_t)d * E_ + e], a);
    qW[(size_t)(b0 + bL) * E_ + e] = a;

    if (ec == 0) {
        float p = 0.f;
        for (int d = eL; d < D_; d += 64) p = fmaf(qs[bL][d], bk[d], p);
#pragma unroll
        for (int off = 32; off >= 1; off >>= 1) p += __shfl_xor(p, off, 64);
        if (eL == 0) qb[b0 + bL] = p;
    }
}

// ---------------------------------------------------------------------------
// Kernel 3: streaming pass over hist (non-temporal). One wave handles HCHUNK
// consecutive h rows. float2 accumulators -> v_pk_fma_f32 (halves FMA instr
// count, raises VMEM issue density). Epilogue: all lanes hold full sums after
// the xor-butterfly; lanes 0..7 each take one row and issue ONE coalesced
// 32B store.
// ---------------------------------------------------------------------------
#define HCHUNK 8

__global__ __launch_bounds__(256) void k_main(const float* __restrict__ cur,
                                              const float* __restrict__ hist,
                                              const float* __restrict__ qW,
                                              const float* __restrict__ qb,
                                              const float* __restrict__ w_cos_p,
                                              const float* __restrict__ w_att_p,
                                              float* __restrict__ out) {
    int wid  = (blockIdx.x * 256 + threadIdx.x) >> 6;
    int lane = threadIdx.x & 63;
    int b  = wid / (H_ / HCHUNK);
    int hc = wid % (H_ / HCHUNK);
    int h0 = hc * HCHUNK;

    const f32x2* cur2 = reinterpret_cast<const f32x2*>(cur + (size_t)b * E_);
    const f32x2* qW2  = reinterpret_cast<const f32x2*>(qW  + (size_t)b * E_);

    f32x2 c2[8], w2[8];
    f32x2 css2 = {0.f, 0.f};
#pragma unroll
    for (int it = 0; it < 4; ++it) {
        int i4 = lane + it * 64;
        c2[2 * it]     = cur2[2 * i4];
        c2[2 * it + 1] = cur2[2 * i4 + 1];
        w2[2 * it]     = qW2[2 * i4];
        w2[2 * it + 1] = qW2[2 * i4 + 1];
        css2 += c2[2 * it] * c2[2 * it] + c2[2 * it + 1] * c2[2 * it + 1];
    }
    float css = css2.x + css2.y;
#pragma unroll
    for (int off = 32; off >= 1; off >>= 1) css += __shfl_xor(css, off, 64);
    float inv_ncur = 1.0f / fmaxf(sqrtf(css), 1e-8f);

    float wc  = w_cos_p[0];
    float wa  = w_att_p[0];
    float qbb = qb[b];
    const float inv_sqrtD = 0.04419417382415922f;  // 1/sqrt(512)

    float ad[HCHUNK], aq[HCHUNK], as_[HCHUNK];

    // Phase A: intra-lane accumulation, all rows, packed fp32
#pragma unroll
    for (int j = 0; j < HCHUNK; ++j) {
        const f32x4* h4 = reinterpret_cast<const f32x4*>(
            hist + ((size_t)b * H_ + (h0 + j)) * E_);
        f32x2 d2 = {0.f, 0.f}, q2 = {0.f, 0.f}, s2 = {0.f, 0.f};
#pragma unroll
        for (int it = 0; it < 4; ++it) {
            f32x4 hv = __builtin_nontemporal_load(&h4[lane + it * 64]);
            f32x2 hlo = {hv.x, hv.y};
            f32x2 hhi = {hv.z, hv.w};
            d2 += hlo * c2[2 * it] + hhi * c2[2 * it + 1];
            q2 += hlo * w2[2 * it] + hhi * w2[2 * it + 1];
            s2 += hlo * hlo        + hhi * hhi;
        }
        ad[j]  = d2.x + d2.y;
        aq[j]  = q2.x + q2.y;
        as_[j] = s2.x + s2.y;
    }

    // Phase B: batched butterflies (full sum lands in every lane)
#pragma unroll
    for (int off = 32; off >= 1; off >>= 1) {
#pragma unroll
        for (int j = 0; j < HCHUNK; ++j) {
            ad[j]  += __shfl_xor(ad[j],  off, 64);
            aq[j]  += __shfl_xor(aq[j],  off, 64);
            as_[j] += __shfl_xor(as_[j], off, 64);
        }
    }

    // Epilogue: lane j takes row j, one coalesced store
    float sd = ad[0], sq = aq[0], ss = as_[0];
#pragma unroll
    for (int j = 1; j < HCHUNK; ++j) {
        bool m = (lane == j);
        sd = m ? ad[j]  : sd;
        sq = m ? aq[j]  : sq;
        ss = m ? as_[j] : ss;
    }
    if (lane < HCHUNK) {
        float n_hist = fmaxf(sqrtf(ss), 1e-8f);
        float cosv   = sd * inv_ncur / n_hist;
        float score  = (sq + qbb) * inv_sqrtD;
        out[(size_t)b * H_ + h0 + lane] = wa * score + wc * cosv;
    }
}

// ---------------------------------------------------------------------------
extern "C" void kernel_launch(void* const* d_in, const int* in_sizes, int n_in,
                              void* d_out, int out_size, void* d_ws, size_t ws_size,
                              hipStream_t stream) {
    const float* cur   = (const float*)d_in[0];
    const float* hist  = (const float*)d_in[1];
    const float* Wq    = (const float*)d_in[2];
    const float* bq    = (const float*)d_in[3];
    const float* Wk    = (const float*)d_in[4];
    const float* bk    = (const float*)d_in[5];
    const float* w_cos = (const float*)d_in[6];
    const float* w_att = (const float*)d_in[7];
    float* out = (float*)d_out;

    float* ws = (float*)d_ws;
    float* q  = ws;                        // B*D floats
    float* qW = ws + (size_t)B_ * D_;      // B*E floats
    float* qb = qW + (size_t)B_ * E_;      // B   floats

    // q = cur @ Wq.T + bq   (4096 waves -> 1024 blocks)
    k_q<<<(B_ / 4) * (D_ / 4) / 4, 256, 0, stream>>>(cur, Wq, bq, q);
    // qW = q @ Wk ; qb = q . bk   (512 blocks: 32 b-groups x 16 e-chunks)
    k_qw<<<512, 256, 0, stream>>>(q, Wk, bk, qW, qb);
    // streaming fused pass (32768 waves -> 8192 blocks)
    k_main<<<B_ * (H_ / HCHUNK) / 4, 256, 0, stream>>>(cur, hist, qW, qb,
                                                       w_cos, w_att, out);
}

// Round 6
// 188.260 us; speedup vs baseline: 1.3287x; 1.0085x over previous
//
#include <hip/hip_runtime.h>
#include <hip/hip_bf16.h>

#define B_ 128
#define H_ 2048
#define E_ 1024
#define D_ 512

typedef float f32x2 __attribute__((ext_vector_type(2)));
typedef float f32x4 __attribute__((ext_vector_type(4)));

// ---------------------------------------------------------------------------
// Kernel 1: q[b,d] = dot(cur[b,:], Wq[d,:]) + bq[d]
// 4b x 4d register tile per wave.
// ---------------------------------------------------------------------------
__global__ __launch_bounds__(256) void k_q(const float* __restrict__ cur,
                                           const float* __restrict__ Wq,
                                           const float* __restrict__ bq,
                                           float* __restrict__ q) {
    int wid  = (blockIdx.x * 256 + threadIdx.x) >> 6;
    int lane = threadIdx.x & 63;
    int bg = wid >> 7;            // D_/4 = 128 d-groups per b-group
    int dg = wid & 127;
    int b0 = bg * 4, d0 = dg * 4;

    float4 c[4][4];
#pragma unroll
    for (int i = 0; i < 4; ++i) {
        const float4* cur4 =
            reinterpret_cast<const float4*>(cur + (size_t)(b0 + i) * E_);
#pragma unroll
        for (int it = 0; it < 4; ++it) c[i][it] = cur4[lane + it * 64];
    }

#pragma unroll
    for (int dd = 0; dd < 4; ++dd) {
        const float4* wq4 =
            reinterpret_cast<const float4*>(Wq + (size_t)(d0 + dd) * E_);
        float4 w[4];
#pragma unroll
        for (int it = 0; it < 4; ++it) w[it] = wq4[lane + it * 64];

        float acc[4] = {0.f, 0.f, 0.f, 0.f};
#pragma unroll
        for (int i = 0; i < 4; ++i)
#pragma unroll
            for (int it = 0; it < 4; ++it)
                acc[i] += c[i][it].x * w[it].x + c[i][it].y * w[it].y +
                          c[i][it].z * w[it].z + c[i][it].w * w[it].w;
#pragma unroll
        for (int off = 32; off >= 1; off >>= 1)
#pragma unroll
            for (int i = 0; i < 4; ++i) acc[i] += __shfl_xor(acc[i], off, 64);

        if (lane == 0) {
            float bqv = bq[d0 + dd];
#pragma unroll
            for (int i = 0; i < 4; ++i)
                q[(size_t)(b0 + i) * D_ + (d0 + dd)] = acc[i] + bqv;
        }
    }
}

// ---------------------------------------------------------------------------
// Kernel 2: qW[b,e] = sum_d q[b,d]*Wk[d,e];  qb[b] = sum_d q[b,d]*bk[d]
// 512 blocks: 32 b-groups(4) x 16 e-chunks(64). Wk slice read ONCE per block.
// Wave w handles b0+w, so qb reduces with a pure 64-lane butterfly.
// ---------------------------------------------------------------------------
__global__ __launch_bounds__(256) void k_qw(const float* __restrict__ q,
                                            const float* __restrict__ Wk,
                                            const float* __restrict__ bk,
                                            float* __restrict__ qW,
                                            float* __restrict__ qb) {
    __shared__ float qs[4][D_];
    int blk = blockIdx.x;
    int bg  = blk >> 4;           // 0..31
    int ec  = blk & 15;           // 0..15
    int t   = threadIdx.x;
    int b0  = bg * 4;

    for (int i = t; i < 4 * D_; i += 256)
        qs[i >> 9][i & (D_ - 1)] = q[(size_t)(b0 + (i >> 9)) * D_ + (i & (D_ - 1))];
    __syncthreads();

    int eL = t & 63;              // lane
    int bL = t >> 6;              // wave id = local b
    int e  = ec * 64 + eL;

    float a = 0.f;
#pragma unroll 16
    for (int d = 0; d < D_; ++d)
        a = fmaf(qs[bL][d], Wk[(size_t)d * E_ + e], a);
    qW[(size_t)(b0 + bL) * E_ + e] = a;

    if (ec == 0) {
        float p = 0.f;
        for (int d = eL; d < D_; d += 64) p = fmaf(qs[bL][d], bk[d], p);
#pragma unroll
        for (int off = 32; off >= 1; off >>= 1) p += __shfl_xor(p, off, 64);
        if (eL == 0) qb[b0 + bL] = p;
    }
}

// ---------------------------------------------------------------------------
// Kernel 3: streaming pass over hist (non-temporal). One wave handles HCHUNK
// consecutive h rows. Phase A is SOFTWARE-PIPELINED: row j+1's 4 loads issue
// before row j's FMAs consume (2-row ping-pong register buffer; full unroll
// makes the j&1 selection static -> stays in registers). float2 accumulators
// -> v_pk_fma_f32. Epilogue: lanes 0..7 each take one row, one coalesced
// 32B store.
// ---------------------------------------------------------------------------
#define HCHUNK 8

__global__ __launch_bounds__(256) void k_main(const float* __restrict__ cur,
                                              const float* __restrict__ hist,
                                              const float* __restrict__ qW,
                                              const float* __restrict__ qb,
                                              const float* __restrict__ w_cos_p,
                                              const float* __restrict__ w_att_p,
                                              float* __restrict__ out) {
    int wid  = (blockIdx.x * 256 + threadIdx.x) >> 6;
    int lane = threadIdx.x & 63;
    int b  = wid / (H_ / HCHUNK);
    int hc = wid % (H_ / HCHUNK);
    int h0 = hc * HCHUNK;

    const f32x2* cur2 = reinterpret_cast<const f32x2*>(cur + (size_t)b * E_);
    const f32x2* qW2  = reinterpret_cast<const f32x2*>(qW  + (size_t)b * E_);

    f32x2 c2[8], w2[8];
    f32x2 css2 = {0.f, 0.f};
#pragma unroll
    for (int it = 0; it < 4; ++it) {
        int i4 = lane + it * 64;
        c2[2 * it]     = cur2[2 * i4];
        c2[2 * it + 1] = cur2[2 * i4 + 1];
        w2[2 * it]     = qW2[2 * i4];
        w2[2 * it + 1] = qW2[2 * i4 + 1];
        css2 += c2[2 * it] * c2[2 * it] + c2[2 * it + 1] * c2[2 * it + 1];
    }
    float css = css2.x + css2.y;
#pragma unroll
    for (int off = 32; off >= 1; off >>= 1) css += __shfl_xor(css, off, 64);
    float inv_ncur = 1.0f / fmaxf(sqrtf(css), 1e-8f);

    float wc  = w_cos_p[0];
    float wa  = w_att_p[0];
    float qbb = qb[b];
    const float inv_sqrtD = 0.04419417382415922f;  // 1/sqrt(512)

    float ad[HCHUNK], aq[HCHUNK], as_[HCHUNK];

    const float* rowbase = hist + ((size_t)b * H_ + h0) * E_;

    f32x4 pa[4], pb[4];

    // prologue: load row 0 into pa
#pragma unroll
    for (int it = 0; it < 4; ++it)
        pa[it] = __builtin_nontemporal_load(
            reinterpret_cast<const f32x4*>(rowbase) + lane + it * 64);

    // Phase A: pipelined — issue row j+1 loads, then FMA row j
#pragma unroll
    for (int j = 0; j < HCHUNK; ++j) {
        f32x4* curb = (j & 1) ? pb : pa;   // static after full unroll
        f32x4* nxtb = (j & 1) ? pa : pb;

        if (j + 1 < HCHUNK) {
            const f32x4* rn = reinterpret_cast<const f32x4*>(
                rowbase + (size_t)(j + 1) * E_);
#pragma unroll
            for (int it = 0; it < 4; ++it)
                nxtb[it] = __builtin_nontemporal_load(&rn[lane + it * 64]);
        }

        f32x2 d2 = {0.f, 0.f}, q2 = {0.f, 0.f}, s2 = {0.f, 0.f};
#pragma unroll
        for (int it = 0; it < 4; ++it) {
            f32x4 hv = curb[it];
            f32x2 hlo = {hv.x, hv.y};
            f32x2 hhi = {hv.z, hv.w};
            d2 += hlo * c2[2 * it] + hhi * c2[2 * it + 1];
            q2 += hlo * w2[2 * it] + hhi * w2[2 * it + 1];
            s2 += hlo * hlo        + hhi * hhi;
        }
        ad[j]  = d2.x + d2.y;
        aq[j]  = q2.x + q2.y;
        as_[j] = s2.x + s2.y;
    }

    // Phase B: batched butterflies (full sum lands in every lane)
#pragma unroll
    for (int off = 32; off >= 1; off >>= 1) {
#pragma unroll
        for (int j = 0; j < HCHUNK; ++j) {
            ad[j]  += __shfl_xor(ad[j],  off, 64);
            aq[j]  += __shfl_xor(aq[j],  off, 64);
            as_[j] += __shfl_xor(as_[j], off, 64);
        }
    }

    // Epilogue: lane j takes row j, one coalesced store
    float sd = ad[0], sq = aq[0], ss = as_[0];
#pragma unroll
    for (int j = 1; j < HCHUNK; ++j) {
        bool m = (lane == j);
        sd = m ? ad[j]  : sd;
        sq = m ? aq[j]  : sq;
        ss = m ? as_[j] : ss;
    }
    if (lane < HCHUNK) {
        float n_hist = fmaxf(sqrtf(ss), 1e-8f);
        float cosv   = sd * inv_ncur / n_hist;
        float score  = (sq + qbb) * inv_sqrtD;
        out[(size_t)b * H_ + h0 + lane] = wa * score + wc * cosv;
    }
}

// ---------------------------------------------------------------------------
extern "C" void kernel_launch(void* const* d_in, const int* in_sizes, int n_in,
                              void* d_out, int out_size, void* d_ws, size_t ws_size,
                              hipStream_t stream) {
    const float* cur   = (const float*)d_in[0];
    const float* hist  = (const float*)d_in[1];
    const float* Wq    = (const float*)d_in[2];
    const float* bq    = (const float*)d_in[3];
    const float* Wk    = (const float*)d_in[4];
    const float* bk    = (const float*)d_in[5];
    const float* w_cos = (const float*)d_in[6];
    const float* w_att = (const float*)d_in[7];
    float* out = (float*)d_out;

    float* ws = (float*)d_ws;
    float* q  = ws;                        // B*D floats
    float* qW = ws + (size_t)B_ * D_;      // B*E floats
    float* qb = qW + (size_t)B_ * E_;      // B   floats

    // q = cur @ Wq.T + bq   (4096 waves -> 1024 blocks)
    k_q<<<(B_ / 4) * (D_ / 4) / 4, 256, 0, stream>>>(cur, Wq, bq, q);
    // qW = q @ Wk ; qb = q . bk   (512 blocks: 32 b-groups x 16 e-chunks)
    k_qw<<<512, 256, 0, stream>>>(q, Wk, bk, qW, qb);
    // streaming fused pass (32768 waves -> 8192 blocks)
    k_main<<<B_ * (H_ / HCHUNK) / 4, 256, 0, stream>>>(cur, hist, qW, qb,
                                                       w_cos, w_att, out);
}